// Round 2
// baseline (2498.935 us; speedup 1.0000x reference)
//
#include <hip/hip_runtime.h>
#include <stdint.h>

#define NN 100000
#define NE 1600000
#define FIN 602
#define KP1 608      // 19 * 32, zero-padded K for layer-1 GEMM
#define H 256
#define C 42
#define NP2 48       // padded N for layer-2 GEMM (3 tiles of 16)

typedef __bf16 bf16;
typedef __bf16 bf16x8 __attribute__((ext_vector_type(8)));
typedef float f32x4 __attribute__((ext_vector_type(4)));

__device__ __forceinline__ float b2f(bf16 v) { return (float)v; }
__device__ __forceinline__ bf16 f2b(float v) { return (bf16)v; }

// ---------------- degree / norm ----------------

__global__ void k_init_deg(int* __restrict__ deg) {
    int i = blockIdx.x * 256 + threadIdx.x;
    if (i < NN) deg[i] = 1;  // self loop
}

__global__ void k_deg(const int* __restrict__ dst, int* __restrict__ deg) {
    int e = blockIdx.x * 256 + threadIdx.x;
    if (e < NE) atomicAdd(&deg[dst[e]], 1);
}

__global__ void k_dinv(const int* __restrict__ deg, float* __restrict__ dinv) {
    int i = blockIdx.x * 256 + threadIdx.x;
    if (i < NN) dinv[i] = 1.0f / sqrtf((float)deg[i]);
}

// ---------------- weight transposes + fp32->bf16 convert ----------------

// W1 fp32 [602][256] -> W1T bf16 [256][608] (zero-padded K)
__global__ void k_transpose_w1(const float* __restrict__ w1, bf16* __restrict__ w1t) {
    int idx = blockIdx.x * 256 + threadIdx.x;  // grid covers 256*608 exactly
    int n = idx / KP1;
    int k = idx % KP1;
    w1t[idx] = (k < FIN) ? f2b(w1[(size_t)k * H + n]) : (bf16)0.0f;
}

// W2 fp32 [256][42] -> W2T bf16 [48][256] (zero-padded N)
__global__ void k_transpose_w2(const float* __restrict__ w2, bf16* __restrict__ w2t) {
    int idx = blockIdx.x * 256 + threadIdx.x;  // grid covers 48*256 exactly
    int n = idx >> 8;
    int k = idx & 255;
    w2t[idx] = (n < C) ? f2b(w2[(size_t)k * C + n]) : (bf16)0.0f;
}

// ---------------- GEMM1: h1[NN][256] = bf16(x)[NN][602] @ bf16(W1) ----------------
// block = 256 threads = 4 waves; block covers 16 rows x 256 cols.
// wave w covers n in [w*64, w*64+64) as 4 tiles of 16.
// A-frag (16x16x32 bf16): lane holds A[m=lane&15][k=(lane>>4)*8 + j]
// C/D: col=lane&15, row=(lane>>4)*4 + reg

__global__ __launch_bounds__(256) void k_gemm1(const float* __restrict__ x,
                                               const bf16* __restrict__ w1t,
                                               bf16* __restrict__ h1) {
    const int tid = threadIdx.x;
    const int wave = tid >> 6;
    const int lane = tid & 63;
    const int q = lane >> 4;
    const int r = lane & 15;
    const int row0 = blockIdx.x << 4;

    f32x4 acc[4] = {{0.f, 0.f, 0.f, 0.f}, {0.f, 0.f, 0.f, 0.f},
                    {0.f, 0.f, 0.f, 0.f}, {0.f, 0.f, 0.f, 0.f}};

    const float* arow = x + (size_t)(row0 + r) * FIN;

    for (int kk = 0; kk < 19; ++kk) {
        const int k0 = kk * 32 + q * 8;
        union { bf16 s[8]; bf16x8 v; } ua;
        if (k0 + 8 <= FIN) {
            // 8B-aligned: row byte offset mult of 8 (602*4), k0 floats mult of 32B
            const float2* p = (const float2*)(arow + k0);
            float2 f0 = p[0], f1 = p[1], f2 = p[2], f3 = p[3];
            ua.s[0] = f2b(f0.x); ua.s[1] = f2b(f0.y);
            ua.s[2] = f2b(f1.x); ua.s[3] = f2b(f1.y);
            ua.s[4] = f2b(f2.x); ua.s[5] = f2b(f2.y);
            ua.s[6] = f2b(f3.x); ua.s[7] = f2b(f3.y);
        } else {
#pragma unroll
            for (int j = 0; j < 8; ++j)
                ua.s[j] = (k0 + j < FIN) ? f2b(arow[k0 + j]) : (bf16)0.0f;
        }
#pragma unroll
        for (int t = 0; t < 4; ++t) {
            const bf16* bp = w1t + (size_t)(wave * 64 + t * 16 + r) * KP1 + k0;
            union { uint4 u; bf16x8 v; } ub;
            ub.u = *(const uint4*)bp;  // 16B aligned: row stride 1216B, k0*2 mult of 16
            acc[t] = __builtin_amdgcn_mfma_f32_16x16x32_bf16(ua.v, ub.v, acc[t], 0, 0, 0);
        }
    }
#pragma unroll
    for (int t = 0; t < 4; ++t) {
        const int col = wave * 64 + t * 16 + r;
#pragma unroll
        for (int rr = 0; rr < 4; ++rr) {
            const int m = q * 4 + rr;
            h1[(size_t)(row0 + m) * H + col] = f2b(acc[t][rr]);
        }
    }
}

// ---------------- layer-1 aggregation ----------------

__global__ void k_initagg1(const bf16* __restrict__ h1, const float* __restrict__ dinv,
                           float* __restrict__ agg1) {
    size_t i = (size_t)blockIdx.x * 256 + threadIdx.x;  // grid covers NN*H exactly
    int node = (int)(i >> 8);
    float dv = dinv[node];
    agg1[i] = b2f(h1[i]) * dv * dv;
}

__global__ void k_scatter1(const int* __restrict__ src, const int* __restrict__ dst,
                           const bf16* __restrict__ h1, const float* __restrict__ dinv,
                           float* __restrict__ agg1) {
    int e = blockIdx.x;
    int s = src[e], d = dst[e];
    float wgt = dinv[s] * dinv[d];
    int f = threadIdx.x;
    atomicAdd(&agg1[(size_t)d * H + f], b2f(h1[(size_t)s * H + f]) * wgt);
}

__global__ void k_relu1(const float* __restrict__ agg1, const float* __restrict__ b1,
                        bf16* __restrict__ hb) {
    size_t i = (size_t)blockIdx.x * 256 + threadIdx.x;  // grid covers NN*H exactly
    int f = (int)(i & 255);
    float v = agg1[i] + b1[f];
    hb[i] = f2b(v > 0.f ? v : 0.f);
}

// ---------------- GEMM2: h2[NN][42] = hb[NN][256] @ W2 ----------------
// block = 256 threads = 4 waves; wave w covers rows [blk*64 + w*16, +16), n in [0,48) as 3 tiles.

__global__ __launch_bounds__(256) void k_gemm2(const bf16* __restrict__ hb,
                                               const bf16* __restrict__ w2t,
                                               bf16* __restrict__ h2) {
    const int tid = threadIdx.x;
    const int wave = tid >> 6;
    const int lane = tid & 63;
    const int q = lane >> 4;
    const int r = lane & 15;
    const int row0 = blockIdx.x * 64 + wave * 16;

    int arow_i = row0 + r;
    if (arow_i >= NN) arow_i = NN - 1;  // clamp: garbage rows only affect unstored D rows
    const bf16* arow = hb + (size_t)arow_i * H;

    f32x4 acc[3] = {{0.f, 0.f, 0.f, 0.f}, {0.f, 0.f, 0.f, 0.f}, {0.f, 0.f, 0.f, 0.f}};

    for (int kk = 0; kk < 8; ++kk) {
        const int k0 = kk * 32 + q * 8;
        union { uint4 u; bf16x8 v; } ua;
        ua.u = *(const uint4*)(arow + k0);  // 16B aligned: row stride 512B
#pragma unroll
        for (int t = 0; t < 3; ++t) {
            const bf16* bp = w2t + (size_t)(t * 16 + r) * H + k0;
            union { uint4 u; bf16x8 v; } ub;
            ub.u = *(const uint4*)bp;
            acc[t] = __builtin_amdgcn_mfma_f32_16x16x32_bf16(ua.v, ub.v, acc[t], 0, 0, 0);
        }
    }
#pragma unroll
    for (int t = 0; t < 3; ++t) {
        const int col = t * 16 + r;
        if (col < C) {
#pragma unroll
            for (int rr = 0; rr < 4; ++rr) {
                const int m = row0 + q * 4 + rr;
                if (m < NN) h2[(size_t)m * C + col] = f2b(acc[t][rr]);
            }
        }
    }
}

// ---------------- layer-2 aggregation + log_softmax ----------------

__global__ void k_initagg2(const bf16* __restrict__ h2, const float* __restrict__ dinv,
                           float* __restrict__ agg2) {
    int node = blockIdx.x;
    int c = threadIdx.x;
    if (c < C) {
        float dv = dinv[node];
        agg2[(size_t)node * C + c] = b2f(h2[(size_t)node * C + c]) * dv * dv;
    }
}

__global__ void k_scatter2(const int* __restrict__ src, const int* __restrict__ dst,
                           const bf16* __restrict__ h2, const float* __restrict__ dinv,
                           float* __restrict__ agg2) {
    int e = blockIdx.x;
    int s = src[e], d = dst[e];
    int c = threadIdx.x;
    if (c < C) {
        float wgt = dinv[s] * dinv[d];
        atomicAdd(&agg2[(size_t)d * C + c], b2f(h2[(size_t)s * C + c]) * wgt);
    }
}

__global__ void k_logsoftmax(const float* __restrict__ agg2, const float* __restrict__ b2,
                             float* __restrict__ out) {
    int node = blockIdx.x;
    int c = threadIdx.x;  // block = 64
    float v = (c < C) ? agg2[(size_t)node * C + c] + b2[c] : -INFINITY;
    float m = v;
#pragma unroll
    for (int o = 32; o > 0; o >>= 1) m = fmaxf(m, __shfl_xor(m, o, 64));
    float ex = (c < C) ? expf(v - m) : 0.f;
    float s = ex;
#pragma unroll
    for (int o = 32; o > 0; o >>= 1) s += __shfl_xor(s, o, 64);
    if (c < C) out[(size_t)node * C + c] = (v - m) - logf(s);
}

// ---------------- launch ----------------

extern "C" void kernel_launch(void* const* d_in, const int* in_sizes, int n_in,
                              void* d_out, int out_size, void* d_ws, size_t ws_size,
                              hipStream_t stream) {
    const float* x  = (const float*)d_in[0];  // fp32 [NN][602]
    const int*   ei = (const int*)d_in[1];    // int32 [2][NE]
    const float* w1 = (const float*)d_in[2];  // fp32 [602][256]
    const float* b1 = (const float*)d_in[3];  // fp32 [256]
    const float* w2 = (const float*)d_in[4];  // fp32 [256][42]
    const float* b2 = (const float*)d_in[5];  // fp32 [42]
    float* out = (float*)d_out;               // fp32 [NN][42]

    const int* src = ei;
    const int* dst = ei + NE;

    char* base = (char*)d_ws;
    size_t off = 0;
    auto alloc = [&](size_t bytes) -> void* {
        void* p = base + off;
        off += (bytes + 255) & ~(size_t)255;
        return p;
    };
    int*   deg  = (int*)alloc((size_t)NN * 4);
    float* dinv = (float*)alloc((size_t)NN * 4);
    bf16*  w1t  = (bf16*)alloc((size_t)H * KP1 * 2);
    bf16*  w2t  = (bf16*)alloc((size_t)NP2 * H * 2);
    bf16*  h1   = (bf16*)alloc((size_t)NN * H * 2);   // reused as hb (relu out)
    float* agg1 = (float*)alloc((size_t)NN * H * 4);
    // h2 / agg2 overlay agg1's region (agg1 dead after k_relu1)
    bf16*  h2   = (bf16*)agg1;
    float* agg2 = (float*)((char*)agg1 + (((size_t)NN * C * 2 + 255) & ~(size_t)255));
    (void)ws_size;

    // degree + norm
    k_init_deg<<<dim3((NN + 255) / 256), dim3(256), 0, stream>>>(deg);
    k_deg<<<dim3((NE + 255) / 256), dim3(256), 0, stream>>>(dst, deg);
    k_dinv<<<dim3((NN + 255) / 256), dim3(256), 0, stream>>>(deg, dinv);

    // weights
    k_transpose_w1<<<dim3(KP1), dim3(256), 0, stream>>>(w1, w1t);  // 608*256 elems
    k_transpose_w2<<<dim3(NP2), dim3(256), 0, stream>>>(w2, w2t);  // 48*256 elems

    // layer 1
    k_gemm1<<<dim3(NN / 16), dim3(256), 0, stream>>>(x, w1t, h1);
    k_initagg1<<<dim3(NN * H / 256), dim3(256), 0, stream>>>(h1, dinv, agg1);
    k_scatter1<<<dim3(NE), dim3(H), 0, stream>>>(src, dst, h1, dinv, agg1);
    k_relu1<<<dim3(NN * H / 256), dim3(256), 0, stream>>>(agg1, b1, h1);  // hb overwrites h1

    // layer 2
    k_gemm2<<<dim3((NN + 63) / 64), dim3(256), 0, stream>>>(h1, w2t, h2);
    k_initagg2<<<dim3(NN), dim3(64), 0, stream>>>(h2, dinv, agg2);
    k_scatter2<<<dim3(NE), dim3(64), 0, stream>>>(src, dst, h2, dinv, agg2);
    k_logsoftmax<<<dim3(NN), dim3(64), 0, stream>>>(agg2, b2, out);
}

// Round 3
// 1005.883 us; speedup vs baseline: 2.4843x; 2.4843x over previous
//
#include <hip/hip_runtime.h>
#include <stdint.h>

#define NN 100000
#define NE 1600000
#define FIN 602
#define KP1 608      // 19 * 32, zero-padded K for layer-1 GEMM
#define H 256
#define C 42
#define NP2 48       // padded N for layer-2 GEMM (3 tiles of 16)
#define NB1 98       // ceil(NN / 1024) scan blocks

typedef __bf16 bf16;
typedef __bf16 bf16x8 __attribute__((ext_vector_type(8)));
typedef float f32x4 __attribute__((ext_vector_type(4)));

__device__ __forceinline__ float b2f(bf16 v) { return (float)v; }
__device__ __forceinline__ bf16 f2b(float v) { return (bf16)v; }
__device__ __forceinline__ float us2f(unsigned short u) {
    union { unsigned int i; float f; } w; w.i = ((unsigned int)u) << 16; return w.f;
}

// ---------------- CSR build ----------------

__global__ void k_zero(int* __restrict__ p, int n) {
    int i = blockIdx.x * 256 + threadIdx.x;
    if (i < n) p[i] = 0;
}

__global__ void k_count(const int* __restrict__ dst, int* __restrict__ cnt) {
    int e = blockIdx.x * 256 + threadIdx.x;
    if (e < NE) atomicAdd(&cnt[dst[e]], 1);
}

__global__ void k_dinv(const int* __restrict__ cnt, float* __restrict__ dinv) {
    int i = blockIdx.x * 256 + threadIdx.x;
    if (i < NN) dinv[i] = rsqrtf((float)(cnt[i] + 1));  // +1 self loop
}

// scan step 1: per-block (1024 elems) exclusive scan + block sums
__global__ __launch_bounds__(256) void k_scan1(const int* __restrict__ cnt,
                                               int* __restrict__ excl, int* __restrict__ bsum) {
    __shared__ int ts[256];
    const int tid = threadIdx.x;
    const int base = blockIdx.x * 1024 + tid * 4;
    int v[4];
#pragma unroll
    for (int j = 0; j < 4; ++j) v[j] = (base + j < NN) ? cnt[base + j] : 0;
    int s = v[0] + v[1] + v[2] + v[3];
    ts[tid] = s;
    __syncthreads();
    for (int off = 1; off < 256; off <<= 1) {
        int t = (tid >= off) ? ts[tid - off] : 0;
        __syncthreads();
        if (tid >= off) ts[tid] += t;
        __syncthreads();
    }
    int prefix = ts[tid] - s;  // exclusive across threads
    if (tid == 255) bsum[blockIdx.x] = ts[255];
    int run = prefix;
#pragma unroll
    for (int j = 0; j < 4; ++j) {
        if (base + j < NN) excl[base + j] = run;
        run += v[j];
    }
}

// scan step 2: exclusive scan of NB1 block sums (single block, 128 threads)
__global__ __launch_bounds__(128) void k_scan2(int* __restrict__ bsum) {
    __shared__ int ts[128];
    const int tid = threadIdx.x;
    int v = (tid < NB1) ? bsum[tid] : 0;
    ts[tid] = v;
    __syncthreads();
    for (int off = 1; off < 128; off <<= 1) {
        int t = (tid >= off) ? ts[tid - off] : 0;
        __syncthreads();
        if (tid >= off) ts[tid] += t;
        __syncthreads();
    }
    if (tid < NB1) bsum[tid] = ts[tid] - v;
}

// scan step 3: add block offsets -> rowptr, cursor
__global__ __launch_bounds__(256) void k_scan3(const int* __restrict__ excl, const int* __restrict__ bsum,
                                               int* __restrict__ rowptr, int* __restrict__ cursor) {
    const int tid = threadIdx.x;
    const int base = blockIdx.x * 1024 + tid * 4;
    const int add = bsum[blockIdx.x];
#pragma unroll
    for (int j = 0; j < 4; ++j) {
        int i = base + j;
        if (i < NN) { int r = excl[i] + add; rowptr[i] = r; cursor[i] = r; }
    }
    if (blockIdx.x == 0 && tid == 0) rowptr[NN] = NE;
}

__global__ void k_fill(const int* __restrict__ src, const int* __restrict__ dst,
                       int* __restrict__ cursor, int* __restrict__ esrc) {
    int e = blockIdx.x * 256 + threadIdx.x;
    if (e < NE) {
        int d = dst[e];
        int pos = atomicAdd(&cursor[d], 1);
        esrc[pos] = src[e];
    }
}

// ---------------- weight transposes + fp32->bf16 convert ----------------

__global__ void k_transpose_w1(const float* __restrict__ w1, bf16* __restrict__ w1t) {
    int idx = blockIdx.x * 256 + threadIdx.x;  // grid covers 256*608 exactly
    int n = idx / KP1;
    int k = idx % KP1;
    w1t[idx] = (k < FIN) ? f2b(w1[(size_t)k * H + n]) : (bf16)0.0f;
}

__global__ void k_transpose_w2(const float* __restrict__ w2, bf16* __restrict__ w2t) {
    int idx = blockIdx.x * 256 + threadIdx.x;  // grid covers 48*256 exactly
    int n = idx >> 8;
    int k = idx & 255;
    w2t[idx] = (n < C) ? f2b(w2[(size_t)k * C + n]) : (bf16)0.0f;
}

// ---------------- GEMM1: h1[NN][256] = bf16(x)[NN][602] @ bf16(W1) ----------------

__global__ __launch_bounds__(256) void k_gemm1(const float* __restrict__ x,
                                               const bf16* __restrict__ w1t,
                                               bf16* __restrict__ h1) {
    const int tid = threadIdx.x;
    const int wave = tid >> 6;
    const int lane = tid & 63;
    const int q = lane >> 4;
    const int r = lane & 15;
    const int row0 = blockIdx.x << 4;

    f32x4 acc[4] = {{0.f, 0.f, 0.f, 0.f}, {0.f, 0.f, 0.f, 0.f},
                    {0.f, 0.f, 0.f, 0.f}, {0.f, 0.f, 0.f, 0.f}};

    const float* arow = x + (size_t)(row0 + r) * FIN;

    for (int kk = 0; kk < 19; ++kk) {
        const int k0 = kk * 32 + q * 8;
        union { bf16 s[8]; bf16x8 v; } ua;
        if (k0 + 8 <= FIN) {
            const float2* p = (const float2*)(arow + k0);
            float2 f0 = p[0], f1 = p[1], f2 = p[2], f3 = p[3];
            ua.s[0] = f2b(f0.x); ua.s[1] = f2b(f0.y);
            ua.s[2] = f2b(f1.x); ua.s[3] = f2b(f1.y);
            ua.s[4] = f2b(f2.x); ua.s[5] = f2b(f2.y);
            ua.s[6] = f2b(f3.x); ua.s[7] = f2b(f3.y);
        } else {
#pragma unroll
            for (int j = 0; j < 8; ++j)
                ua.s[j] = (k0 + j < FIN) ? f2b(arow[k0 + j]) : (bf16)0.0f;
        }
#pragma unroll
        for (int t = 0; t < 4; ++t) {
            const bf16* bp = w1t + (size_t)(wave * 64 + t * 16 + r) * KP1 + k0;
            union { uint4 u; bf16x8 v; } ub;
            ub.u = *(const uint4*)bp;
            acc[t] = __builtin_amdgcn_mfma_f32_16x16x32_bf16(ua.v, ub.v, acc[t], 0, 0, 0);
        }
    }
#pragma unroll
    for (int t = 0; t < 4; ++t) {
        const int col = wave * 64 + t * 16 + r;
#pragma unroll
        for (int rr = 0; rr < 4; ++rr) {
            const int m = q * 4 + rr;
            h1[(size_t)(row0 + m) * H + col] = f2b(acc[t][rr]);
        }
    }
}

// ---------------- layer-1 pull aggregation + bias + relu (fused) ----------------
// one wave per node; thread t handles feats [4t, 4t+4)

__global__ __launch_bounds__(64) void k_gather1(const int* __restrict__ rowptr,
                                                const int* __restrict__ esrc,
                                                const bf16* __restrict__ h1,
                                                const float* __restrict__ dinv,
                                                const float* __restrict__ b1,
                                                bf16* __restrict__ hb) {
    const int n = blockIdx.x;
    const int tid = threadIdx.x;
    const float dn = dinv[n];

    // self loop
    uint2 u = ((const uint2*)(h1 + (size_t)n * H))[tid];
    float ws = dn * dn;
    float a0 = us2f((unsigned short)(u.x & 0xffff)) * ws;
    float a1 = us2f((unsigned short)(u.x >> 16)) * ws;
    float a2 = us2f((unsigned short)(u.y & 0xffff)) * ws;
    float a3 = us2f((unsigned short)(u.y >> 16)) * ws;

    const int beg = rowptr[n], end = rowptr[n + 1];
    for (int j = beg; j < end; ++j) {
        int s = esrc[j];                        // broadcast
        float w = dinv[s] * dn;                 // broadcast
        uint2 v = ((const uint2*)(h1 + (size_t)s * H))[tid];
        a0 += us2f((unsigned short)(v.x & 0xffff)) * w;
        a1 += us2f((unsigned short)(v.x >> 16)) * w;
        a2 += us2f((unsigned short)(v.y & 0xffff)) * w;
        a3 += us2f((unsigned short)(v.y >> 16)) * w;
    }

    float4 bb = ((const float4*)b1)[tid];
    a0 += bb.x; a1 += bb.y; a2 += bb.z; a3 += bb.w;
    a0 = a0 > 0.f ? a0 : 0.f;
    a1 = a1 > 0.f ? a1 : 0.f;
    a2 = a2 > 0.f ? a2 : 0.f;
    a3 = a3 > 0.f ? a3 : 0.f;

    union { unsigned short s[4]; uint2 u; } pk;
    union { bf16 b; unsigned short s; } cv;
    cv.b = f2b(a0); pk.s[0] = cv.s;
    cv.b = f2b(a1); pk.s[1] = cv.s;
    cv.b = f2b(a2); pk.s[2] = cv.s;
    cv.b = f2b(a3); pk.s[3] = cv.s;
    ((uint2*)(hb + (size_t)n * H))[tid] = pk.u;
}

// ---------------- GEMM2: h2[NN][42] = hb[NN][256] @ W2 ----------------

__global__ __launch_bounds__(256) void k_gemm2(const bf16* __restrict__ hb,
                                               const bf16* __restrict__ w2t,
                                               bf16* __restrict__ h2) {
    const int tid = threadIdx.x;
    const int wave = tid >> 6;
    const int lane = tid & 63;
    const int q = lane >> 4;
    const int r = lane & 15;
    const int row0 = blockIdx.x * 64 + wave * 16;

    int arow_i = row0 + r;
    if (arow_i >= NN) arow_i = NN - 1;  // clamp: garbage rows only affect unstored D rows
    const bf16* arow = hb + (size_t)arow_i * H;

    f32x4 acc[3] = {{0.f, 0.f, 0.f, 0.f}, {0.f, 0.f, 0.f, 0.f}, {0.f, 0.f, 0.f, 0.f}};

    for (int kk = 0; kk < 8; ++kk) {
        const int k0 = kk * 32 + q * 8;
        union { uint4 u; bf16x8 v; } ua;
        ua.u = *(const uint4*)(arow + k0);
#pragma unroll
        for (int t = 0; t < 3; ++t) {
            const bf16* bp = w2t + (size_t)(t * 16 + r) * H + k0;
            union { uint4 u; bf16x8 v; } ub;
            ub.u = *(const uint4*)bp;
            acc[t] = __builtin_amdgcn_mfma_f32_16x16x32_bf16(ua.v, ub.v, acc[t], 0, 0, 0);
        }
    }
#pragma unroll
    for (int t = 0; t < 3; ++t) {
        const int col = t * 16 + r;
        if (col < C) {
#pragma unroll
            for (int rr = 0; rr < 4; ++rr) {
                const int m = row0 + q * 4 + rr;
                if (m < NN) h2[(size_t)m * C + col] = f2b(acc[t][rr]);
            }
        }
    }
}

// ---------------- layer-2 pull aggregation + bias + log_softmax (fused) ----------------
// one wave per node; thread c < C active for feature work

__global__ __launch_bounds__(64) void k_gather2(const int* __restrict__ rowptr,
                                                const int* __restrict__ esrc,
                                                const bf16* __restrict__ h2,
                                                const float* __restrict__ dinv,
                                                const float* __restrict__ b2,
                                                float* __restrict__ out) {
    const int n = blockIdx.x;
    const int c = threadIdx.x;
    const float dn = dinv[n];

    float acc = 0.f;
    if (c < C) acc = b2f(h2[(size_t)n * C + c]) * dn * dn;  // self loop

    const int beg = rowptr[n], end = rowptr[n + 1];
    for (int j = beg; j < end; ++j) {
        int s = esrc[j];
        float w = dinv[s] * dn;
        if (c < C) acc += b2f(h2[(size_t)s * C + c]) * w;
    }

    float v = (c < C) ? acc + b2[c] : -INFINITY;
    float m = v;
#pragma unroll
    for (int o = 32; o > 0; o >>= 1) m = fmaxf(m, __shfl_xor(m, o, 64));
    float ex = (c < C) ? expf(v - m) : 0.f;
    float s = ex;
#pragma unroll
    for (int o = 32; o > 0; o >>= 1) s += __shfl_xor(s, o, 64);
    if (c < C) out[(size_t)n * C + c] = (v - m) - logf(s);
}

// ---------------- launch ----------------

extern "C" void kernel_launch(void* const* d_in, const int* in_sizes, int n_in,
                              void* d_out, int out_size, void* d_ws, size_t ws_size,
                              hipStream_t stream) {
    const float* x  = (const float*)d_in[0];  // fp32 [NN][602]
    const int*   ei = (const int*)d_in[1];    // int32 [2][NE]
    const float* w1 = (const float*)d_in[2];  // fp32 [602][256]
    const float* b1 = (const float*)d_in[3];  // fp32 [256]
    const float* w2 = (const float*)d_in[4];  // fp32 [256][42]
    const float* b2 = (const float*)d_in[5];  // fp32 [42]
    float* out = (float*)d_out;               // fp32 [NN][42]

    const int* src = ei;
    const int* dst = ei + NE;

    char* base = (char*)d_ws;
    size_t off = 0;
    auto alloc = [&](size_t bytes) -> void* {
        void* p = base + off;
        off += (bytes + 255) & ~(size_t)255;
        return p;
    };
    int*   cnt    = (int*)alloc((size_t)NN * 4);
    float* dinv   = (float*)alloc((size_t)NN * 4);
    int*   excl   = (int*)alloc((size_t)NN * 4);
    int*   bsum   = (int*)alloc(128 * 4);
    int*   rowptr = (int*)alloc((size_t)(NN + 1) * 4);
    int*   cursor = (int*)alloc((size_t)NN * 4);
    int*   esrc   = (int*)alloc((size_t)NE * 4);
    bf16*  w1t    = (bf16*)alloc((size_t)H * KP1 * 2);
    bf16*  w2t    = (bf16*)alloc((size_t)NP2 * H * 2);
    bf16*  h1     = (bf16*)alloc((size_t)NN * H * 2);
    bf16*  hb     = (bf16*)alloc((size_t)NN * H * 2);
    bf16*  h2     = (bf16*)alloc((size_t)NN * C * 2);
    (void)ws_size;

    // CSR build + norm
    k_zero<<<dim3((NN + 255) / 256), dim3(256), 0, stream>>>(cnt, NN);
    k_count<<<dim3((NE + 255) / 256), dim3(256), 0, stream>>>(dst, cnt);
    k_dinv<<<dim3((NN + 255) / 256), dim3(256), 0, stream>>>(cnt, dinv);
    k_scan1<<<dim3(NB1), dim3(256), 0, stream>>>(cnt, excl, bsum);
    k_scan2<<<dim3(1), dim3(128), 0, stream>>>(bsum);
    k_scan3<<<dim3(NB1), dim3(256), 0, stream>>>(excl, bsum, rowptr, cursor);
    k_fill<<<dim3((NE + 255) / 256), dim3(256), 0, stream>>>(src, dst, cursor, esrc);

    // weights
    k_transpose_w1<<<dim3(KP1), dim3(256), 0, stream>>>(w1, w1t);
    k_transpose_w2<<<dim3(NP2), dim3(256), 0, stream>>>(w2, w2t);

    // layer 1
    k_gemm1<<<dim3(NN / 16), dim3(256), 0, stream>>>(x, w1t, h1);
    k_gather1<<<dim3(NN), dim3(64), 0, stream>>>(rowptr, esrc, h1, dinv, b1, hb);

    // layer 2
    k_gemm2<<<dim3((NN + 63) / 64), dim3(256), 0, stream>>>(hb, w2t, h2);
    k_gather2<<<dim3(NN), dim3(64), 0, stream>>>(rowptr, esrc, h2, dinv, b2, out);
}

// Round 4
// 799.430 us; speedup vs baseline: 3.1259x; 1.2582x over previous
//
#include <hip/hip_runtime.h>
#include <stdint.h>

#define NN 100000
#define NE 1600000
#define FIN 602
#define KP1 608      // 19 * 32, zero-padded K for layer-1 GEMM
#define H 256
#define C 42
#define NP2 48       // padded N for layer-2 GEMM (3 tiles of 16)
#define NB1 98       // ceil(NN / 1024) scan blocks

typedef __bf16 bf16;
typedef __bf16 bf16x8 __attribute__((ext_vector_type(8)));
typedef float f32x4 __attribute__((ext_vector_type(4)));

__device__ __forceinline__ float b2f(bf16 v) { return (float)v; }
__device__ __forceinline__ bf16 f2b(float v) { return (bf16)v; }
__device__ __forceinline__ float us2f(unsigned short u) {
    union { unsigned int i; float f; } w; w.i = ((unsigned int)u) << 16; return w.f;
}

// ---------------- CSR build ----------------

__global__ void k_zero(int* __restrict__ p, int n) {
    int i = blockIdx.x * 256 + threadIdx.x;
    if (i < n) p[i] = 0;
}

__global__ void k_count(const int* __restrict__ dst, int* __restrict__ cnt) {
    int e = blockIdx.x * 256 + threadIdx.x;
    if (e < NE) atomicAdd(&cnt[dst[e]], 1);
}

__global__ void k_dinv(const int* __restrict__ cnt, float* __restrict__ dinv) {
    int i = blockIdx.x * 256 + threadIdx.x;
    if (i < NN) dinv[i] = rsqrtf((float)(cnt[i] + 1));  // +1 self loop
}

__global__ __launch_bounds__(256) void k_scan1(const int* __restrict__ cnt,
                                               int* __restrict__ excl, int* __restrict__ bsum) {
    __shared__ int ts[256];
    const int tid = threadIdx.x;
    const int base = blockIdx.x * 1024 + tid * 4;
    int v[4];
#pragma unroll
    for (int j = 0; j < 4; ++j) v[j] = (base + j < NN) ? cnt[base + j] : 0;
    int s = v[0] + v[1] + v[2] + v[3];
    ts[tid] = s;
    __syncthreads();
    for (int off = 1; off < 256; off <<= 1) {
        int t = (tid >= off) ? ts[tid - off] : 0;
        __syncthreads();
        if (tid >= off) ts[tid] += t;
        __syncthreads();
    }
    int prefix = ts[tid] - s;
    if (tid == 255) bsum[blockIdx.x] = ts[255];
    int run = prefix;
#pragma unroll
    for (int j = 0; j < 4; ++j) {
        if (base + j < NN) excl[base + j] = run;
        run += v[j];
    }
}

__global__ __launch_bounds__(128) void k_scan2(int* __restrict__ bsum) {
    __shared__ int ts[128];
    const int tid = threadIdx.x;
    int v = (tid < NB1) ? bsum[tid] : 0;
    ts[tid] = v;
    __syncthreads();
    for (int off = 1; off < 128; off <<= 1) {
        int t = (tid >= off) ? ts[tid - off] : 0;
        __syncthreads();
        if (tid >= off) ts[tid] += t;
        __syncthreads();
    }
    if (tid < NB1) bsum[tid] = ts[tid] - v;
}

__global__ __launch_bounds__(256) void k_scan3(const int* __restrict__ excl, const int* __restrict__ bsum,
                                               int* __restrict__ rowptr, int* __restrict__ cursor) {
    const int tid = threadIdx.x;
    const int base = blockIdx.x * 1024 + tid * 4;
    const int add = bsum[blockIdx.x];
#pragma unroll
    for (int j = 0; j < 4; ++j) {
        int i = base + j;
        if (i < NN) { int r = excl[i] + add; rowptr[i] = r; cursor[i] = r; }
    }
    if (blockIdx.x == 0 && tid == 0) rowptr[NN] = NE;
}

__global__ void k_fill(const int* __restrict__ src, const int* __restrict__ dst,
                       int* __restrict__ cursor, int* __restrict__ esrc) {
    int e = blockIdx.x * 256 + threadIdx.x;
    if (e < NE) {
        int d = dst[e];
        int pos = atomicAdd(&cursor[d], 1);
        esrc[pos] = src[e];
    }
}

// ---------------- weight transposes + fp32->bf16 convert ----------------

__global__ void k_transpose_w1(const float* __restrict__ w1, bf16* __restrict__ w1t) {
    int idx = blockIdx.x * 256 + threadIdx.x;  // grid covers 256*608 exactly
    int n = idx / KP1;
    int k = idx % KP1;
    w1t[idx] = (k < FIN) ? f2b(w1[(size_t)k * H + n]) : (bf16)0.0f;
}

__global__ void k_transpose_w2(const float* __restrict__ w2, bf16* __restrict__ w2t) {
    int idx = blockIdx.x * 256 + threadIdx.x;  // grid covers 48*256 exactly
    int n = idx >> 8;
    int k = idx & 255;
    w2t[idx] = (n < C) ? f2b(w2[(size_t)k * C + n]) : (bf16)0.0f;
}

// ---------------- GEMM1: h1[NN][256] = bf16(x)[NN][602] @ bf16(W1) ----------------
// 64-row tile, LDS-staged A. 4 waves; wave w covers cols [w*64, +64) (4 col-tiles),
// all 4 row-tiles. 16 MFMA per wave per K-step.
// A-frag: lane(q=lane>>4, r=lane&15) holds A[m=r][k=q*8+j]; C/D: col=r, row=q*4+reg.

__global__ __launch_bounds__(256) void k_gemm1(const float* __restrict__ x,
                                               const bf16* __restrict__ w1t,
                                               bf16* __restrict__ h1) {
    __shared__ bf16 As[64 * 32];  // row-major, row stride 32 (64 B)
    const int tid = threadIdx.x;
    const int wave = tid >> 6;
    const int lane = tid & 63;
    const int q = lane >> 4;
    const int r = lane & 15;
    const int row0 = blockIdx.x * 64;

    // staging: thread t -> row (t>>2), 8-float segment (t&3)
    const int srow = tid >> 2;
    const int sseg = tid & 3;
    int gsrow = row0 + srow;
    if (gsrow >= NN) gsrow = NN - 1;  // clamp; stores guarded
    const float* xrow = x + (size_t)gsrow * FIN + sseg * 8;

    f32x4 acc[4][4];  // [row-tile][col-tile]
#pragma unroll
    for (int a = 0; a < 4; ++a)
#pragma unroll
        for (int b = 0; b < 4; ++b) acc[a][b] = (f32x4){0.f, 0.f, 0.f, 0.f};

    const bf16* bbase = w1t + (size_t)(wave * 64) * KP1;

    for (int kk = 0; kk < 19; ++kk) {
        const int k0 = kk * 32;
        const int c0 = k0 + sseg * 8;
        union { bf16 s[8]; uint4 u; } pk;
        if (c0 + 8 <= FIN) {
            // 8B-aligned float2 loads (row byte offset mult of 8)
            const float2* p = (const float2*)(xrow + k0);
            float2 f0 = p[0], f1 = p[1], f2 = p[2], f3 = p[3];
            pk.s[0] = f2b(f0.x); pk.s[1] = f2b(f0.y);
            pk.s[2] = f2b(f1.x); pk.s[3] = f2b(f1.y);
            pk.s[4] = f2b(f2.x); pk.s[5] = f2b(f2.y);
            pk.s[6] = f2b(f3.x); pk.s[7] = f2b(f3.y);
        } else {
#pragma unroll
            for (int j = 0; j < 8; ++j)
                pk.s[j] = (c0 + j < FIN) ? f2b(xrow[k0 + j]) : (bf16)0.0f;
        }
        __syncthreads();  // prev-iter readers done
        *(uint4*)(As + srow * 32 + sseg * 8) = pk.u;
        __syncthreads();  // writes visible

        bf16x8 af[4];
#pragma unroll
        for (int rt = 0; rt < 4; ++rt) {
            union { uint4 u; bf16x8 v; } ua;
            ua.u = *(const uint4*)(As + (rt * 16 + r) * 32 + q * 8);
            af[rt] = ua.v;
        }
#pragma unroll
        for (int ct = 0; ct < 4; ++ct) {
            const bf16* bp = bbase + (size_t)(ct * 16 + r) * KP1 + k0 + q * 8;
            union { uint4 u; bf16x8 v; } ub;
            ub.u = *(const uint4*)bp;
#pragma unroll
            for (int rt = 0; rt < 4; ++rt)
                acc[rt][ct] = __builtin_amdgcn_mfma_f32_16x16x32_bf16(af[rt], ub.v, acc[rt][ct], 0, 0, 0);
        }
    }

#pragma unroll
    for (int rt = 0; rt < 4; ++rt) {
#pragma unroll
        for (int ct = 0; ct < 4; ++ct) {
            const int col = wave * 64 + ct * 16 + r;
#pragma unroll
            for (int rr = 0; rr < 4; ++rr) {
                const int m = row0 + rt * 16 + q * 4 + rr;
                if (m < NN) h1[(size_t)m * H + col] = f2b(acc[rt][ct][rr]);
            }
        }
    }
}

// ---------------- layer-1 pull aggregation + bias + relu (fused) ----------------

__global__ __launch_bounds__(64) void k_gather1(const int* __restrict__ rowptr,
                                                const int* __restrict__ esrc,
                                                const bf16* __restrict__ h1,
                                                const float* __restrict__ dinv,
                                                const float* __restrict__ b1,
                                                bf16* __restrict__ hb) {
    const int n = blockIdx.x;
    const int tid = threadIdx.x;
    const float dn = dinv[n];

    uint2 u = ((const uint2*)(h1 + (size_t)n * H))[tid];
    float ws = dn * dn;
    float a0 = us2f((unsigned short)(u.x & 0xffff)) * ws;
    float a1 = us2f((unsigned short)(u.x >> 16)) * ws;
    float a2 = us2f((unsigned short)(u.y & 0xffff)) * ws;
    float a3 = us2f((unsigned short)(u.y >> 16)) * ws;

    const int beg = rowptr[n], end = rowptr[n + 1];
    int j = beg;
    // unroll-by-4: 4 independent load chains in flight
    for (; j + 3 < end; j += 4) {
        int s0 = esrc[j], s1 = esrc[j + 1], s2 = esrc[j + 2], s3 = esrc[j + 3];
        float w0 = dinv[s0] * dn, w1 = dinv[s1] * dn, w2 = dinv[s2] * dn, w3 = dinv[s3] * dn;
        uint2 v0 = ((const uint2*)(h1 + (size_t)s0 * H))[tid];
        uint2 v1 = ((const uint2*)(h1 + (size_t)s1 * H))[tid];
        uint2 v2 = ((const uint2*)(h1 + (size_t)s2 * H))[tid];
        uint2 v3 = ((const uint2*)(h1 + (size_t)s3 * H))[tid];
        a0 += us2f((unsigned short)(v0.x & 0xffff)) * w0;
        a1 += us2f((unsigned short)(v0.x >> 16)) * w0;
        a2 += us2f((unsigned short)(v0.y & 0xffff)) * w0;
        a3 += us2f((unsigned short)(v0.y >> 16)) * w0;
        a0 += us2f((unsigned short)(v1.x & 0xffff)) * w1;
        a1 += us2f((unsigned short)(v1.x >> 16)) * w1;
        a2 += us2f((unsigned short)(v1.y & 0xffff)) * w1;
        a3 += us2f((unsigned short)(v1.y >> 16)) * w1;
        a0 += us2f((unsigned short)(v2.x & 0xffff)) * w2;
        a1 += us2f((unsigned short)(v2.x >> 16)) * w2;
        a2 += us2f((unsigned short)(v2.y & 0xffff)) * w2;
        a3 += us2f((unsigned short)(v2.y >> 16)) * w2;
        a0 += us2f((unsigned short)(v3.x & 0xffff)) * w3;
        a1 += us2f((unsigned short)(v3.x >> 16)) * w3;
        a2 += us2f((unsigned short)(v3.y & 0xffff)) * w3;
        a3 += us2f((unsigned short)(v3.y >> 16)) * w3;
    }
    for (; j < end; ++j) {
        int s = esrc[j];
        float w = dinv[s] * dn;
        uint2 v = ((const uint2*)(h1 + (size_t)s * H))[tid];
        a0 += us2f((unsigned short)(v.x & 0xffff)) * w;
        a1 += us2f((unsigned short)(v.x >> 16)) * w;
        a2 += us2f((unsigned short)(v.y & 0xffff)) * w;
        a3 += us2f((unsigned short)(v.y >> 16)) * w;
    }

    float4 bb = ((const float4*)b1)[tid];
    a0 += bb.x; a1 += bb.y; a2 += bb.z; a3 += bb.w;
    a0 = a0 > 0.f ? a0 : 0.f;
    a1 = a1 > 0.f ? a1 : 0.f;
    a2 = a2 > 0.f ? a2 : 0.f;
    a3 = a3 > 0.f ? a3 : 0.f;

    union { unsigned short s[4]; uint2 u; } pk;
    union { bf16 b; unsigned short s; } cv;
    cv.b = f2b(a0); pk.s[0] = cv.s;
    cv.b = f2b(a1); pk.s[1] = cv.s;
    cv.b = f2b(a2); pk.s[2] = cv.s;
    cv.b = f2b(a3); pk.s[3] = cv.s;
    ((uint2*)(hb + (size_t)n * H))[tid] = pk.u;
}

// ---------------- GEMM2: h2[NN][42] = hb[NN][256] @ W2 ----------------
// 256-row tile, LDS-staged A. wave w covers rows [w*64, +64) (4 row-tiles), 3 col-tiles.

__global__ __launch_bounds__(256) void k_gemm2(const bf16* __restrict__ hb,
                                               const bf16* __restrict__ w2t,
                                               bf16* __restrict__ h2) {
    __shared__ bf16 As[256 * 32];  // 16 KB
    const int tid = threadIdx.x;
    const int wave = tid >> 6;
    const int lane = tid & 63;
    const int q = lane >> 4;
    const int r = lane & 15;
    const int row0 = blockIdx.x * 256;

    int gsrow = row0 + tid;
    if (gsrow >= NN) gsrow = NN - 1;
    const bf16* arow = hb + (size_t)gsrow * H;

    f32x4 acc[4][3];
#pragma unroll
    for (int a = 0; a < 4; ++a)
#pragma unroll
        for (int b = 0; b < 3; ++b) acc[a][b] = (f32x4){0.f, 0.f, 0.f, 0.f};

    for (int kk = 0; kk < 8; ++kk) {
        const int k0 = kk * 32;
        // stage: thread t copies its row's 32 bf16 (64 B, 16B-aligned)
        uint4 c0 = *(const uint4*)(arow + k0);
        uint4 c1 = *(const uint4*)(arow + k0 + 8);
        uint4 c2 = *(const uint4*)(arow + k0 + 16);
        uint4 c3 = *(const uint4*)(arow + k0 + 24);
        __syncthreads();
        uint4* ldst = (uint4*)(As + tid * 32);
        ldst[0] = c0; ldst[1] = c1; ldst[2] = c2; ldst[3] = c3;
        __syncthreads();

        bf16x8 af[4];
#pragma unroll
        for (int rt = 0; rt < 4; ++rt) {
            union { uint4 u; bf16x8 v; } ua;
            ua.u = *(const uint4*)(As + (wave * 64 + rt * 16 + r) * 32 + q * 8);
            af[rt] = ua.v;
        }
#pragma unroll
        for (int ct = 0; ct < 3; ++ct) {
            const bf16* bp = w2t + (size_t)(ct * 16 + r) * H + k0 + q * 8;
            union { uint4 u; bf16x8 v; } ub;
            ub.u = *(const uint4*)bp;
#pragma unroll
            for (int rt = 0; rt < 4; ++rt)
                acc[rt][ct] = __builtin_amdgcn_mfma_f32_16x16x32_bf16(af[rt], ub.v, acc[rt][ct], 0, 0, 0);
        }
    }

#pragma unroll
    for (int rt = 0; rt < 4; ++rt) {
#pragma unroll
        for (int ct = 0; ct < 3; ++ct) {
            const int col = ct * 16 + r;
            if (col < C) {
#pragma unroll
                for (int rr = 0; rr < 4; ++rr) {
                    const int m = row0 + wave * 64 + rt * 16 + q * 4 + rr;
                    if (m < NN) h2[(size_t)m * C + col] = f2b(acc[rt][ct][rr]);
                }
            }
        }
    }
}

// ---------------- layer-2 pull aggregation + bias + log_softmax (fused) ----------------

__global__ __launch_bounds__(64) void k_gather2(const int* __restrict__ rowptr,
                                                const int* __restrict__ esrc,
                                                const bf16* __restrict__ h2,
                                                const float* __restrict__ dinv,
                                                const float* __restrict__ b2,
                                                float* __restrict__ out) {
    const int n = blockIdx.x;
    const int c = threadIdx.x;
    const float dn = dinv[n];

    float acc = 0.f;
    if (c < C) acc = b2f(h2[(size_t)n * C + c]) * dn * dn;

    const int beg = rowptr[n], end = rowptr[n + 1];
    int j = beg;
    for (; j + 3 < end; j += 4) {
        int s0 = esrc[j], s1 = esrc[j + 1], s2 = esrc[j + 2], s3 = esrc[j + 3];
        float w0 = dinv[s0] * dn, w1 = dinv[s1] * dn, w2 = dinv[s2] * dn, w3 = dinv[s3] * dn;
        if (c < C) {
            float v0 = b2f(h2[(size_t)s0 * C + c]);
            float v1 = b2f(h2[(size_t)s1 * C + c]);
            float v2 = b2f(h2[(size_t)s2 * C + c]);
            float v3 = b2f(h2[(size_t)s3 * C + c]);
            acc += v0 * w0 + v1 * w1 + v2 * w2 + v3 * w3;
        }
    }
    for (; j < end; ++j) {
        int s = esrc[j];
        float w = dinv[s] * dn;
        if (c < C) acc += b2f(h2[(size_t)s * C + c]) * w;
    }

    float v = (c < C) ? acc + b2[c] : -INFINITY;
    float m = v;
#pragma unroll
    for (int o = 32; o > 0; o >>= 1) m = fmaxf(m, __shfl_xor(m, o, 64));
    float ex = (c < C) ? expf(v - m) : 0.f;
    float s = ex;
#pragma unroll
    for (int o = 32; o > 0; o >>= 1) s += __shfl_xor(s, o, 64);
    if (c < C) out[(size_t)n * C + c] = (v - m) - logf(s);
}

// ---------------- launch ----------------

extern "C" void kernel_launch(void* const* d_in, const int* in_sizes, int n_in,
                              void* d_out, int out_size, void* d_ws, size_t ws_size,
                              hipStream_t stream) {
    const float* x  = (const float*)d_in[0];  // fp32 [NN][602]
    const int*   ei = (const int*)d_in[1];    // int32 [2][NE]
    const float* w1 = (const float*)d_in[2];  // fp32 [602][256]
    const float* b1 = (const float*)d_in[3];  // fp32 [256]
    const float* w2 = (const float*)d_in[4];  // fp32 [256][42]
    const float* b2 = (const float*)d_in[5];  // fp32 [42]
    float* out = (float*)d_out;               // fp32 [NN][42]

    const int* src = ei;
    const int* dst = ei + NE;

    char* base = (char*)d_ws;
    size_t off = 0;
    auto alloc = [&](size_t bytes) -> void* {
        void* p = base + off;
        off += (bytes + 255) & ~(size_t)255;
        return p;
    };
    int*   cnt    = (int*)alloc((size_t)NN * 4);
    float* dinv   = (float*)alloc((size_t)NN * 4);
    int*   excl   = (int*)alloc((size_t)NN * 4);
    int*   bsum   = (int*)alloc(128 * 4);
    int*   rowptr = (int*)alloc((size_t)(NN + 1) * 4);
    int*   cursor = (int*)alloc((size_t)NN * 4);
    int*   esrc   = (int*)alloc((size_t)NE * 4);
    bf16*  w1t    = (bf16*)alloc((size_t)H * KP1 * 2);
    bf16*  w2t    = (bf16*)alloc((size_t)NP2 * H * 2);
    bf16*  h1     = (bf16*)alloc((size_t)NN * H * 2);
    bf16*  hb     = (bf16*)alloc((size_t)NN * H * 2);
    bf16*  h2     = (bf16*)alloc((size_t)NN * C * 2);
    (void)ws_size;

    // CSR build + norm
    k_zero<<<dim3((NN + 255) / 256), dim3(256), 0, stream>>>(cnt, NN);
    k_count<<<dim3((NE + 255) / 256), dim3(256), 0, stream>>>(dst, cnt);
    k_dinv<<<dim3((NN + 255) / 256), dim3(256), 0, stream>>>(cnt, dinv);
    k_scan1<<<dim3(NB1), dim3(256), 0, stream>>>(cnt, excl, bsum);
    k_scan2<<<dim3(1), dim3(128), 0, stream>>>(bsum);
    k_scan3<<<dim3(NB1), dim3(256), 0, stream>>>(excl, bsum, rowptr, cursor);
    k_fill<<<dim3((NE + 255) / 256), dim3(256), 0, stream>>>(src, dst, cursor, esrc);

    // weights
    k_transpose_w1<<<dim3(KP1), dim3(256), 0, stream>>>(w1, w1t);
    k_transpose_w2<<<dim3(NP2), dim3(256), 0, stream>>>(w2, w2t);

    // layer 1
    k_gemm1<<<dim3((NN + 63) / 64), dim3(256), 0, stream>>>(x, w1t, h1);
    k_gather1<<<dim3(NN), dim3(64), 0, stream>>>(rowptr, esrc, h1, dinv, b1, hb);

    // layer 2
    k_gemm2<<<dim3((NN + 255) / 256), dim3(256), 0, stream>>>(hb, w2t, h2);
    k_gather2<<<dim3(NN), dim3(64), 0, stream>>>(rowptr, esrc, h2, dinv, b2, out);
}